// Round 15
// baseline (153.043 us; speedup 1.0000x reference)
//
#include <hip/hip_runtime.h>
#include <cstdint>
#include <cstddef>

// Problem dims
#define Bb 2
#define Ss 2048
#define Dd 1024
#define Hh 16
#define DKk 64

typedef unsigned short ushort_t;
typedef __bf16 bf16x8 __attribute__((ext_vector_type(8)));
typedef float f32x4 __attribute__((ext_vector_type(4)));
typedef unsigned short us8 __attribute__((ext_vector_type(8)));
typedef unsigned short us4 __attribute__((ext_vector_type(4)));

__device__ __forceinline__ ushort_t f2bf(float f) {
  __bf16 h = (__bf16)f;
  return __builtin_bit_cast(unsigned short, h);
}

// global -> LDS direct copy, 16B per lane. LDS dest must be wave-uniform;
// HW writes lane l's data at ldsbase + l*16.
__device__ __forceinline__ void gload_lds16(const void* g, void* l) {
  __builtin_amdgcn_global_load_lds(
      (__attribute__((address_space(1))) void*)(g),
      (__attribute__((address_space(3))) void*)(l),
      16, 0, 0);
}

// ---------------------------------------------------------------- cast fp32->bf16
__global__ __launch_bounds__(256) void cast_k(const float* __restrict__ s,
                                              ushort_t* __restrict__ d, int n8) {
  const int i = blockIdx.x * 256 + threadIdx.x;
  if (i >= n8) return;
  const float4* sp = (const float4*)s;
  float4 a = sp[2 * i], b = sp[2 * i + 1];
  us8 o;
  o[0] = f2bf(a.x); o[1] = f2bf(a.y); o[2] = f2bf(a.z); o[3] = f2bf(a.w);
  o[4] = f2bf(b.x); o[5] = f2bf(b.y); o[6] = f2bf(b.z); o[7] = f2bf(b.w);
  ((us8*)d)[i] = o;
}

// merged cast of the four 1024x1024 weights (wq|wk|wv|wo -> one contiguous
// bf16 region): one dispatch instead of four (saves 3 launch gaps).
__global__ __launch_bounds__(256) void castw_k(const float* __restrict__ s0,
                                               const float* __restrict__ s1,
                                               const float* __restrict__ s2,
                                               const float* __restrict__ s3,
                                               ushort_t* __restrict__ d) {
  const int w = blockIdx.x >> 9;                         // 0..3
  const int i = (blockIdx.x & 511) * 256 + threadIdx.x;  // 0..131071
  const float* s = (w == 0) ? s0 : (w == 1) ? s1 : (w == 2) ? s2 : s3;
  const float4* sp = (const float4*)s;
  float4 a = sp[2 * i], b = sp[2 * i + 1];
  us8 o;
  o[0] = f2bf(a.x); o[1] = f2bf(a.y); o[2] = f2bf(a.z); o[3] = f2bf(a.w);
  o[4] = f2bf(b.x); o[5] = f2bf(b.y); o[6] = f2bf(b.z); o[7] = f2bf(b.w);
  ((us8*)(d + (size_t)w * 1048576))[i] = o;
}

// ---------------------------------------------------------------- GEMM
// y[m][n] = sum_k A[m][k] * W[n][k]  (both row-major, K contiguous)
// BK=64 + XOR-swizzled LDS (the attn-verified stage/read swizzle, identical
// geometry: 64-elem rows, 8x16B slots, slot ^= row&7, linear gload_lds dest
// + pre-swizzled global source + swizzled ds_read_b128). Halves the barrier
// count per K-loop (32 -> 16) and doubles MFMA per sync region.
// MODE 0: QKV projection. N=3072 (wq|wk|wv packed). Epilogue adds bias,
//         scales Q by 0.125*log2(e) (attn softmax runs in exp2 domain),
//         writes Q,K as [b,h,s,dk] bf16 and V transposed as VT [b,h,dk,s].
// MODE 1: output projection. N=1024. Epilogue adds bias, writes fp32 [m][n].
template <int MODE>
__global__ __launch_bounds__(256) void gemm_k(
    const ushort_t* __restrict__ A, const ushort_t* __restrict__ W,
    const float* __restrict__ b0, const float* __restrict__ b1,
    const float* __restrict__ b2,
    ushort_t* __restrict__ oQ, ushort_t* __restrict__ oK,
    ushort_t* __restrict__ oVT, float* __restrict__ oF) {
  constexpr int Kd = 1024;
  __shared__ ushort_t As[128 * 64];   // 16 KB
  __shared__ ushort_t Bs[128 * 64];   // 16 KB
  const int tid = threadIdx.x;
  const int lane = tid & 63;
  const int wave = tid >> 6;
  const int m0 = blockIdx.y * 128;
  const int n0 = blockIdx.x * 128;
  const int lr = lane & 15;
  const int lg = lane >> 4;
  const int s_row = lane >> 3;              // 0..7 within 8-row chunk
  const int s_slot = (lane & 7) ^ s_row;    // pre-swizzled 16B slot (rule 21)
  const int sw = lr & 15 & 7;               // = lr & 7: read-side row&7
  const int ar = (wave >> 1) * 64;   // wave's output row base in tile
  const int bc = (wave & 1) * 64;    // wave's output col base in tile

  f32x4 acc[4][4] = {};

  for (int kt = 0; kt < Kd / 64; ++kt) {
    const int k0 = kt * 64;
#pragma unroll
    for (int c = 0; c < 4; ++c) {
      const int gi = wave * 4 + c;   // 0..15, 8 rows (1KB) each
      const int row = gi * 8 + s_row;
      gload_lds16(A + (size_t)(m0 + row) * Kd + k0 + s_slot * 8,
                  (char*)As + gi * 1024);
      gload_lds16(W + (size_t)(n0 + row) * Kd + k0 + s_slot * 8,
                  (char*)Bs + gi * 1024);
    }
    __syncthreads();  // drains vmcnt before barrier
#pragma unroll
    for (int kk = 0; kk < 2; ++kk) {
      bf16x8 af[4], bfr[4];
#pragma unroll
      for (int i = 0; i < 4; ++i) {
        const int row = ar + i * 16 + lr;
        af[i] = *(const bf16x8*)&As[row * 64 + (((kk * 4 + lg) ^ sw) * 8)];
      }
#pragma unroll
      for (int j = 0; j < 4; ++j) {
        const int row = bc + j * 16 + lr;
        bfr[j] = *(const bf16x8*)&Bs[row * 64 + (((kk * 4 + lg) ^ sw) * 8)];
      }
#pragma unroll
      for (int i = 0; i < 4; ++i)
#pragma unroll
        for (int j = 0; j < 4; ++j)
          acc[i][j] = __builtin_amdgcn_mfma_f32_16x16x32_bf16(af[i], bfr[j],
                                                              acc[i][j], 0, 0, 0);
    }
    __syncthreads();
  }

  // Epilogue. C/D layout: reg r -> row (lg*4 + r), col = lr  [m89-verified]
#pragma unroll
  for (int i = 0; i < 4; ++i) {
    const int mrow = m0 + ar + i * 16 + lg * 4;  // + r
#pragma unroll
    for (int j = 0; j < 4; ++j) {
      const int n = n0 + bc + j * 16 + lr;
      if (MODE == 0) {
        const int sel = n >> 10;       // 0=Q 1=K 2=V (uniform per j)
        const int nn = n & 1023;
        const float bias = (sel == 0 ? b0 : sel == 1 ? b1 : b2)[nn];
        const int h = nn >> 6, dk = nn & 63;
        const int bidx = mrow >> 11;
        const int s = mrow & 2047;     // rows s..s+3 stay in same batch
        const int bh = bidx * Hh + h;
        if (sel == 2) {
          // V transposed: VT[bh][dk][s], 4 consecutive s -> one 8B store
          us4 pk;
#pragma unroll
          for (int r = 0; r < 4; ++r) pk[r] = f2bf(acc[i][j][r] + bias);
          *(us4*)&oVT[((size_t)bh * DKk + dk) * Ss + s] = pk;
        } else {
          ushort_t* dst = (sel == 0) ? oQ : oK;
          // Q: fold 1/sqrt(DK) * log2(e) so attn uses raw v_exp (exp2)
          const float mul = (sel == 0) ? 0.1803368842f : 1.0f;
#pragma unroll
          for (int r = 0; r < 4; ++r)
            dst[((size_t)bh * Ss + (s + r)) * DKk + dk] =
                f2bf((acc[i][j][r] + bias) * mul);
        }
      } else {
        const float bias = b0[n];
#pragma unroll
        for (int r = 0; r < 4; ++r)
          oF[(size_t)(mrow + r) * Dd + n] = acc[i][j][r] + bias;
      }
    }
  }
}

// ---------------------------------------------------------------- flash attention
// Byte-exact v12 (best measured: 80.4us): 4-wave shared K-LDS dbuf, swapped
// QK, LDS-P K=32 PV with operand-swap (O^T accumulation), ones-MFMA l.
// v13 (finer blocks) and v14 (vt-first ordering) both regressed — the
// compiler's v12 schedule is the local optimum for this structure.
__global__ __launch_bounds__(256, 4) void attn_k(const ushort_t* __restrict__ Qg,
                                                 const ushort_t* __restrict__ Kg,
                                                 const ushort_t* __restrict__ Vt,
                                                 ushort_t* __restrict__ AO) {
  __shared__ ushort_t Ks[2][64 * 64];   // 16 KB, double-buffered K tile
  __shared__ ushort_t Pl[4][16 * 72];   // 9 KB, per-wave P (q-major, pad 72)
  const int tid = threadIdx.x, lane = tid & 63, wave = tid >> 6;
  const int bx = blockIdx.x;
  const int bh = bx & 31;                // bh&7 == XCD under round-robin
  const int r_ = bx >> 8;                // 0..3
  const int sub = (bx >> 5) & 7;         // 0..7
  const int g = (3 - r_) * 8 + ((r_ & 1) ? 7 - sub : sub);  // 0..31, heavy 1st
  const int lr = lane & 15, lg = lane >> 4;
  const ushort_t* Qp = Qg + (size_t)bh * Ss * DKk;
  const ushort_t* Kp = Kg + (size_t)bh * Ss * DKk;
  const ushort_t* Vp = Vt + (size_t)bh * DKk * Ss;
  ushort_t* P = Pl[wave];
  const int s_row = lane >> 3;              // 0..7 within 8-row chunk
  const int s_slot = (lane & 7) ^ s_row;    // pre-swizzled 16B slot (rule 21)
  const int sw = lr & 7;
  const int q0 = g * 64 + wave * 16;        // wave's 16 q rows
  const int nt = g + 1;                     // KV tiles of 64

  // stage K tile t into Ks[buf]: wave stages rows wave*16..+15 (2 issues)
  auto stageK = [&](int t, int buf) {
    const int rb = wave * 16;
#pragma unroll
    for (int c = 0; c < 2; ++c)
      gload_lds16(Kp + (size_t)(t * 64 + rb + c * 8 + s_row) * DKk + s_slot * 8,
                  &Ks[buf][(rb + c * 8) * 64]);
  };

  stageK(0, 0);

  // Q fragment (B-operand of 16x16x32): row q0+lr, d = ks*32 + lg*8 ..+8
  bf16x8 qf[2];
#pragma unroll
  for (int ks = 0; ks < 2; ++ks)
    qf[ks] = *(const bf16x8*)&Qp[(size_t)(q0 + lr) * DKk + ks * 32 + lg * 8];

  bf16x8 onesv;
#pragma unroll
  for (int e = 0; e < 8; ++e) onesv[e] = (__bf16)1.0f;

  f32x4 o[4] = {};   // o[dj][r] = O[q = lr][d = dj*16 + lg*4 + r]  (O^T acc)
  f32x4 l4 = {};     // l4[0]: l for q = lr
  float m_ = -3e38f;

  __syncthreads();  // K tile 0 staged (drains vmcnt)

  for (int t = 0; t < nt; ++t) {
    const int cb = t & 1;
    if (t + 1 < nt) stageK(t + 1, cb ^ 1);
    const int j0 = t * 64;
    const bool diag = (t == nt - 1);
    const int nct = diag ? wave + 1 : 4;   // diag k-subtile cap (dct = wave)

    // VT fragments (A-operand of 16x16x32): row d=dj*16+lr, s=j0+ksp*32+lg*8
    bf16x8 vt[4][2];
#pragma unroll
    for (int dj = 0; dj < 4; ++dj)
#pragma unroll
      for (int ksp = 0; ksp < 2; ++ksp)
        vt[dj][ksp] = *(const bf16x8*)&Vp[(size_t)(dj * 16 + lr) * Ss + j0 +
                                          ksp * 32 + lg * 8];

    // ---- S^T = K Q^T : sc[ct][r] = S[q=lr][k = ct*16 + lg*4 + r]
    f32x4 sc[4];
#pragma unroll
    for (int ct = 0; ct < 4; ++ct) {
      if (ct < nct) {
        const int krow = ct * 16 + lr;
        const bf16x8 k0v = *(const bf16x8*)&Ks[cb][krow * 64 + ((lg ^ sw) * 8)];
        const bf16x8 k1v =
            *(const bf16x8*)&Ks[cb][krow * 64 + (((4 | lg) ^ sw) * 8)];
        f32x4 z = {};
        z = __builtin_amdgcn_mfma_f32_16x16x32_bf16(k0v, qf[0], z, 0, 0, 0);
        z = __builtin_amdgcn_mfma_f32_16x16x32_bf16(k1v, qf[1], z, 0, 0, 0);
        sc[ct] = z;
      }
    }
    // causal element mask: only the diag's top k-subtile (ct == wave)
    if (diag) {
#pragma unroll
      for (int ct = 0; ct < 4; ++ct)
        if (ct == nct - 1)
#pragma unroll
          for (int r = 0; r < 4; ++r)
            if (lg * 4 + r > lr) sc[ct][r] = -1e30f;
    }

    // ---- online softmax, exp2 domain, per-lane scalar state (q = lr)
    float mx = -3e38f;
#pragma unroll
    for (int ct = 0; ct < 4; ++ct)
      if (ct < nct)
#pragma unroll
        for (int r = 0; r < 4; ++r) mx = fmaxf(mx, sc[ct][r]);
    mx = fmaxf(mx, __shfl_xor(mx, 16, 64));
    mx = fmaxf(mx, __shfl_xor(mx, 32, 64));
    const float mnew = fmaxf(m_, mx);
    const float fs = __builtin_exp2f(m_ - mnew);
    m_ = mnew;
#pragma unroll
    for (int ct = 0; ct < 4; ++ct) {
      if (ct < nct) {
        float p0 = __builtin_exp2f(sc[ct][0] - m_);
        float p1 = __builtin_exp2f(sc[ct][1] - m_);
        float p2 = __builtin_exp2f(sc[ct][2] - m_);
        float p3 = __builtin_exp2f(sc[ct][3] - m_);
        us4 pk;
        pk[0] = f2bf(p0); pk[1] = f2bf(p1); pk[2] = f2bf(p2); pk[3] = f2bf(p3);
        // P[q = lr][k = ct*16 + lg*4 .. +4]  (one 8B write)
        *(us4*)&P[lr * 72 + ct * 16 + lg * 4] = pk;
      } else {
        us4 zz = {};  // masked k-subtile on diag: exact zeros
        *(us4*)&P[lr * 72 + ct * 16 + lg * 4] = zz;
      }
    }

    // ---- rescale O^T and l (all state at q = lr: direct, no shuffles)
#pragma unroll
    for (int dj = 0; dj < 4; ++dj)
#pragma unroll
      for (int r = 0; r < 4; ++r) o[dj][r] *= fs;
    l4[0] *= fs;

    // LDS write->read ordering within the wave
    asm volatile("s_waitcnt lgkmcnt(0)" ::: "memory");
    bf16x8 pa[2];
#pragma unroll
    for (int ksp = 0; ksp < 2; ++ksp)
      pa[ksp] = *(const bf16x8*)&P[lr * 72 + ksp * 32 + lg * 8];

    // ---- l += rowsum(P) via ones-MFMA: D[m][n=lr] = sum_k P[lr][k]
#pragma unroll
    for (int ksp = 0; ksp < 2; ++ksp)
      l4 = __builtin_amdgcn_mfma_f32_16x16x32_bf16(onesv, pa[ksp], l4, 0, 0, 0);
    // ---- O^T += V^T P^T : D[d_local][q=lr]
#pragma unroll
    for (int dj = 0; dj < 4; ++dj)
#pragma unroll
      for (int ksp = 0; ksp < 2; ++ksp)
        o[dj] = __builtin_amdgcn_mfma_f32_16x16x32_bf16(vt[dj][ksp], pa[ksp],
                                                        o[dj], 0, 0, 0);

    __syncthreads();  // stage(t+1) complete (vmcnt0) + buffer handoff
  }

  // ---- normalize and write AO [b*S+s][h*64+d] bf16 (8B packed over d)
  const int bb = bh >> 4, hh = bh & 15;
  const float inv = 1.0f / l4[0];
#pragma unroll
  for (int dj = 0; dj < 4; ++dj) {
    us4 pk;
#pragma unroll
    for (int r = 0; r < 4; ++r) pk[r] = f2bf(o[dj][r] * inv);
    *(us4*)&AO[((size_t)bb * Ss + q0 + lr) * Dd + hh * 64 + dj * 16 + lg * 4] =
        pk;
  }
}

// ---------------------------------------------------------------- launch
extern "C" void kernel_launch(void* const* d_in, const int* in_sizes, int n_in,
                              void* d_out, int out_size, void* d_ws, size_t ws_size,
                              hipStream_t stream) {
  const float* x  = (const float*)d_in[0];
  // d_in[1] = causal mask (tril) — hardcoded in attn kernel
  const float* wq = (const float*)d_in[2];
  const float* bq = (const float*)d_in[3];
  const float* wk = (const float*)d_in[4];
  const float* bk = (const float*)d_in[5];
  const float* wv = (const float*)d_in[6];
  const float* bv = (const float*)d_in[7];
  const float* wo = (const float*)d_in[8];
  const float* bo = (const float*)d_in[9];

  ushort_t* ws   = (ushort_t*)d_ws;
  ushort_t* xb   = ws;                   // [4096][1024] bf16 (8MB), reused as AO
  ushort_t* wqkv = xb + 4096 * 1024;     // [3072][1024] bf16 (6MB)
  ushort_t* wob  = wqkv + 3072 * 1024;   // [1024][1024] bf16 (2MB), contiguous
  ushort_t* Qb   = wob + 1024 * 1024;    // [2,16,2048,64] bf16 (8MB)
  ushort_t* Kb   = Qb + 4194304;         // (8MB)
  ushort_t* VTb  = Kb + 4194304;         // [2,16,64,2048] bf16 (8MB)
  ushort_t* AOb  = xb;                   // reuse: x dead after QKV GEMM

  cast_k<<<2048, 256, 0, stream>>>(x, xb, 524288);
  castw_k<<<2048, 256, 0, stream>>>(wq, wk, wv, wo, wqkv);  // wob follows wqkv

  gemm_k<0><<<dim3(24, 32), 256, 0, stream>>>(xb, wqkv, bq, bk, bv, Qb, Kb, VTb,
                                              nullptr);
  attn_k<<<1024, 256, 0, stream>>>(Qb, Kb, VTb, AOb);
  gemm_k<1><<<dim3(8, 32), 256, 0, stream>>>(AOb, wob, bo, nullptr, nullptr,
                                             nullptr, nullptr, nullptr,
                                             (float*)d_out);
}

// Round 17
// 140.956 us; speedup vs baseline: 1.0858x; 1.0858x over previous
//
#include <hip/hip_runtime.h>
#include <cstdint>
#include <cstddef>

// Problem dims
#define Bb 2
#define Ss 2048
#define Dd 1024
#define Hh 16
#define DKk 64

typedef unsigned short ushort_t;
typedef __bf16 bf16x8 __attribute__((ext_vector_type(8)));
typedef float f32x4 __attribute__((ext_vector_type(4)));
typedef unsigned short us8 __attribute__((ext_vector_type(8)));
typedef unsigned short us4 __attribute__((ext_vector_type(4)));

__device__ __forceinline__ ushort_t f2bf(float f) {
  __bf16 h = (__bf16)f;
  return __builtin_bit_cast(unsigned short, h);
}

// global -> LDS direct copy, 16B per lane. LDS dest must be wave-uniform;
// HW writes lane l's data at ldsbase + l*16.
__device__ __forceinline__ void gload_lds16(const void* g, void* l) {
  __builtin_amdgcn_global_load_lds(
      (__attribute__((address_space(1))) void*)(g),
      (__attribute__((address_space(3))) void*)(l),
      16, 0, 0);
}

// ---------------------------------------------------------------- casts
// One dispatch for x (blocks 0..2047) + the four weights (blocks 2048..4095,
// 512 each -> contiguous bf16 wq|wk|wv|wo).
__global__ __launch_bounds__(256) void cast_all(
    const float* __restrict__ x, const float* __restrict__ w0,
    const float* __restrict__ w1, const float* __restrict__ w2,
    const float* __restrict__ w3, ushort_t* __restrict__ dx,
    ushort_t* __restrict__ dw) {
  const int b = blockIdx.x;
  const float* s;
  ushort_t* d;
  int i;
  if (b < 2048) {
    s = x; d = dx; i = b * 256 + threadIdx.x;
  } else {
    const int w = (b - 2048) >> 9;
    s = (w == 0) ? w0 : (w == 1) ? w1 : (w == 2) ? w2 : w3;
    d = dw + (size_t)w * 1048576;
    i = ((b - 2048) & 511) * 256 + threadIdx.x;
  }
  const float4* sp = (const float4*)s;
  float4 a = sp[2 * i], c = sp[2 * i + 1];
  us8 o;
  o[0] = f2bf(a.x); o[1] = f2bf(a.y); o[2] = f2bf(a.z); o[3] = f2bf(a.w);
  o[4] = f2bf(c.x); o[5] = f2bf(c.y); o[6] = f2bf(c.z); o[7] = f2bf(c.w);
  ((us8*)d)[i] = o;
}

// ---------------------------------------------------------------- GEMM 0 (QKV)
// y[m][n] = sum_k A[m][k] * W[n][k]; 128x128 tile, BK=32 (r13-verified).
// N=3072 (wq|wk|wv packed). Epilogue adds bias, scales Q by 0.125*log2(e)
// (attn softmax runs in exp2 domain), writes Q,K as [b,h,s,dk] bf16 and V
// transposed as VT [b,h,dk,s].
__global__ __launch_bounds__(256) void gemm0_k(
    const ushort_t* __restrict__ A, const ushort_t* __restrict__ W,
    const float* __restrict__ b0, const float* __restrict__ b1,
    const float* __restrict__ b2,
    ushort_t* __restrict__ oQ, ushort_t* __restrict__ oK,
    ushort_t* __restrict__ oVT) {
  constexpr int Kd = 1024;
  __shared__ ushort_t As[128 * 32];
  __shared__ ushort_t Bs[128 * 32];
  const int tid = threadIdx.x;
  const int lane = tid & 63;
  const int wave = tid >> 6;
  const int m0 = blockIdx.y * 128;
  const int n0 = blockIdx.x * 128;
  const int lr = lane & 15;
  const int lg = lane >> 4;
  const int srow = lane >> 2;        // staging row within 16-row segment
  const int scol = (lane & 3) * 8;   // staging col (elements)
  const int ar = (wave >> 1) * 64;   // wave's output row base in tile
  const int bc = (wave & 1) * 64;    // wave's output col base in tile

  f32x4 acc[4][4] = {};

  for (int kt = 0; kt < Kd / 32; ++kt) {
    const int k0 = kt * 32;
#pragma unroll
    for (int c = 0; c < 2; ++c) {
      const int seg = wave * 2 + c;  // 0..7, 16 rows (1KB) each
      const int row = seg * 16 + srow;
      gload_lds16(A + (size_t)(m0 + row) * Kd + k0 + scol, (char*)As + seg * 1024);
      gload_lds16(W + (size_t)(n0 + row) * Kd + k0 + scol, (char*)Bs + seg * 1024);
    }
    __syncthreads();  // drains vmcnt before barrier
    bf16x8 af[4], bfr[4];
#pragma unroll
    for (int i = 0; i < 4; ++i)
      af[i] = *(const bf16x8*)&As[(ar + i * 16 + lr) * 32 + lg * 8];
#pragma unroll
    for (int j = 0; j < 4; ++j)
      bfr[j] = *(const bf16x8*)&Bs[(bc + j * 16 + lr) * 32 + lg * 8];
#pragma unroll
    for (int i = 0; i < 4; ++i)
#pragma unroll
      for (int j = 0; j < 4; ++j)
        acc[i][j] = __builtin_amdgcn_mfma_f32_16x16x32_bf16(af[i], bfr[j],
                                                            acc[i][j], 0, 0, 0);
    __syncthreads();
  }

  // Epilogue. C/D layout: reg r -> row (lg*4 + r), col = lr  [m89-verified]
#pragma unroll
  for (int i = 0; i < 4; ++i) {
    const int mrow = m0 + ar + i * 16 + lg * 4;  // + r
#pragma unroll
    for (int j = 0; j < 4; ++j) {
      const int n = n0 + bc + j * 16 + lr;
      const int sel = n >> 10;       // 0=Q 1=K 2=V (uniform per j)
      const int nn = n & 1023;
      const float bias = (sel == 0 ? b0 : sel == 1 ? b1 : b2)[nn];
      const int h = nn >> 6, dk = nn & 63;
      const int bidx = mrow >> 11;
      const int s = mrow & 2047;     // rows s..s+3 stay in same batch
      const int bh = bidx * Hh + h;
      if (sel == 2) {
        // V transposed: VT[bh][dk][s], 4 consecutive s -> one 8B store
        us4 pk;
#pragma unroll
        for (int r = 0; r < 4; ++r) pk[r] = f2bf(acc[i][j][r] + bias);
        *(us4*)&oVT[((size_t)bh * DKk + dk) * Ss + s] = pk;
      } else {
        ushort_t* dst = (sel == 0) ? oQ : oK;
        // Q: fold 1/sqrt(DK) * log2(e) so attn uses raw v_exp (exp2)
        const float mul = (sel == 0) ? 0.1803368842f : 1.0f;
#pragma unroll
        for (int r = 0; r < 4; ++r)
          dst[((size_t)bh * Ss + (s + r)) * DKk + dk] =
              f2bf((acc[i][j][r] + bias) * mul);
      }
    }
  }
}

// ---------------------------------------------------------------- GEMM 1 (out)
// BM=128, BN=64, BK=32 -> grid 16x32 = 512 blocks = 2/CU (the 128x128 tile
// gave exactly 256 blocks = 1/CU: a single barrier group per CU, no
// inter-block latency hiding -> residency-starved). Wave w owns rows
// w*32..+31 x all 64 cols: acc[2][4], 8 MFMA/step. Epilogue adds bias,
// writes fp32 [m][n] to d_out.
__global__ __launch_bounds__(256) void gemm1_k(const ushort_t* __restrict__ A,
                                               const ushort_t* __restrict__ W,
                                               const float* __restrict__ b0,
                                               float* __restrict__ oF) {
  constexpr int Kd = 1024;
  __shared__ ushort_t As[128 * 32];  // 8 KB
  __shared__ ushort_t Bs[64 * 32];   // 4 KB
  const int tid = threadIdx.x;
  const int lane = tid & 63;
  const int wave = tid >> 6;
  const int m0 = blockIdx.y * 128;
  const int n0 = blockIdx.x * 64;
  const int lr = lane & 15;
  const int lg = lane >> 4;
  const int srow = lane >> 2;        // staging row within 16-row segment
  const int scol = (lane & 3) * 8;   // staging col (elements)

  f32x4 acc[2][4] = {};

  for (int kt = 0; kt < Kd / 32; ++kt) {
    const int k0 = kt * 32;
    // A: 8 segs of 16 rows; wave stages segs wave*2, wave*2+1
#pragma unroll
    for (int c = 0; c < 2; ++c) {
      const int seg = wave * 2 + c;
      const int row = seg * 16 + srow;
      gload_lds16(A + (size_t)(m0 + row) * Kd + k0 + scol, (char*)As + seg * 1024);
    }
    // B: 4 segs of 16 rows; wave stages seg 'wave'
    {
      const int row = wave * 16 + srow;
      gload_lds16(W + (size_t)(n0 + row) * Kd + k0 + scol, (char*)Bs + wave * 1024);
    }
    __syncthreads();  // drains vmcnt before barrier
    bf16x8 af[2], bfr[4];
#pragma unroll
    for (int i = 0; i < 2; ++i)
      af[i] = *(const bf16x8*)&As[(wave * 32 + i * 16 + lr) * 32 + lg * 8];
#pragma unroll
    for (int j = 0; j < 4; ++j)
      bfr[j] = *(const bf16x8*)&Bs[(j * 16 + lr) * 32 + lg * 8];
#pragma unroll
    for (int i = 0; i < 2; ++i)
#pragma unroll
      for (int j = 0; j < 4; ++j)
        acc[i][j] = __builtin_amdgcn_mfma_f32_16x16x32_bf16(af[i], bfr[j],
                                                            acc[i][j], 0, 0, 0);
    __syncthreads();
  }

  // Epilogue: C/D layout reg r -> row (lg*4 + r), col = lr
#pragma unroll
  for (int i = 0; i < 2; ++i) {
    const int mrow = m0 + wave * 32 + i * 16 + lg * 4;  // + r
#pragma unroll
    for (int j = 0; j < 4; ++j) {
      const int n = n0 + j * 16 + lr;
      const float bias = b0[n];
#pragma unroll
      for (int r = 0; r < 4; ++r)
        oF[(size_t)(mrow + r) * Dd + n] = acc[i][j][r] + bias;
    }
  }
}

// ---------------------------------------------------------------- flash attention
// Byte-exact v12 (best measured: 80.4us): 4-wave shared K-LDS dbuf, swapped
// QK, LDS-P K=32 PV with operand-swap (O^T accumulation), ones-MFMA l.
// v13 (finer blocks) and v14 (vt-first ordering) both regressed — the
// compiler's v12 schedule is the local optimum for this structure.
__global__ __launch_bounds__(256, 4) void attn_k(const ushort_t* __restrict__ Qg,
                                                 const ushort_t* __restrict__ Kg,
                                                 const ushort_t* __restrict__ Vt,
                                                 ushort_t* __restrict__ AO) {
  __shared__ ushort_t Ks[2][64 * 64];   // 16 KB, double-buffered K tile
  __shared__ ushort_t Pl[4][16 * 72];   // 9 KB, per-wave P (q-major, pad 72)
  const int tid = threadIdx.x, lane = tid & 63, wave = tid >> 6;
  const int bx = blockIdx.x;
  const int bh = bx & 31;                // bh&7 == XCD under round-robin
  const int r_ = bx >> 8;                // 0..3
  const int sub = (bx >> 5) & 7;         // 0..7
  const int g = (3 - r_) * 8 + ((r_ & 1) ? 7 - sub : sub);  // 0..31, heavy 1st
  const int lr = lane & 15, lg = lane >> 4;
  const ushort_t* Qp = Qg + (size_t)bh * Ss * DKk;
  const ushort_t* Kp = Kg + (size_t)bh * Ss * DKk;
  const ushort_t* Vp = Vt + (size_t)bh * DKk * Ss;
  ushort_t* P = Pl[wave];
  const int s_row = lane >> 3;              // 0..7 within 8-row chunk
  const int s_slot = (lane & 7) ^ s_row;    // pre-swizzled 16B slot (rule 21)
  const int sw = lr & 7;
  const int q0 = g * 64 + wave * 16;        // wave's 16 q rows
  const int nt = g + 1;                     // KV tiles of 64

  // stage K tile t into Ks[buf]: wave stages rows wave*16..+15 (2 issues)
  auto stageK = [&](int t, int buf) {
    const int rb = wave * 16;
#pragma unroll
    for (int c = 0; c < 2; ++c)
      gload_lds16(Kp + (size_t)(t * 64 + rb + c * 8 + s_row) * DKk + s_slot * 8,
                  &Ks[buf][(rb + c * 8) * 64]);
  };

  stageK(0, 0);

  // Q fragment (B-operand of 16x16x32): row q0+lr, d = ks*32 + lg*8 ..+8
  bf16x8 qf[2];
#pragma unroll
  for (int ks = 0; ks < 2; ++ks)
    qf[ks] = *(const bf16x8*)&Qp[(size_t)(q0 + lr) * DKk + ks * 32 + lg * 8];

  bf16x8 onesv;
#pragma unroll
  for (int e = 0; e < 8; ++e) onesv[e] = (__bf16)1.0f;

  f32x4 o[4] = {};   // o[dj][r] = O[q = lr][d = dj*16 + lg*4 + r]  (O^T acc)
  f32x4 l4 = {};     // l4[0]: l for q = lr
  float m_ = -3e38f;

  __syncthreads();  // K tile 0 staged (drains vmcnt)

  for (int t = 0; t < nt; ++t) {
    const int cb = t & 1;
    if (t + 1 < nt) stageK(t + 1, cb ^ 1);
    const int j0 = t * 64;
    const bool diag = (t == nt - 1);
    const int nct = diag ? wave + 1 : 4;   // diag k-subtile cap (dct = wave)

    // VT fragments (A-operand of 16x16x32): row d=dj*16+lr, s=j0+ksp*32+lg*8
    bf16x8 vt[4][2];
#pragma unroll
    for (int dj = 0; dj < 4; ++dj)
#pragma unroll
      for (int ksp = 0; ksp < 2; ++ksp)
        vt[dj][ksp] = *(const bf16x8*)&Vp[(size_t)(dj * 16 + lr) * Ss + j0 +
                                          ksp * 32 + lg * 8];

    // ---- S^T = K Q^T : sc[ct][r] = S[q=lr][k = ct*16 + lg*4 + r]
    f32x4 sc[4];
#pragma unroll
    for (int ct = 0; ct < 4; ++ct) {
      if (ct < nct) {
        const int krow = ct * 16 + lr;
        const bf16x8 k0v = *(const bf16x8*)&Ks[cb][krow * 64 + ((lg ^ sw) * 8)];
        const bf16x8 k1v =
            *(const bf16x8*)&Ks[cb][krow * 64 + (((4 | lg) ^ sw) * 8)];
        f32x4 z = {};
        z = __builtin_amdgcn_mfma_f32_16x16x32_bf16(k0v, qf[0], z, 0, 0, 0);
        z = __builtin_amdgcn_mfma_f32_16x16x32_bf16(k1v, qf[1], z, 0, 0, 0);
        sc[ct] = z;
      }
    }
    // causal element mask: only the diag's top k-subtile (ct == wave)
    if (diag) {
#pragma unroll
      for (int ct = 0; ct < 4; ++ct)
        if (ct == nct - 1)
#pragma unroll
          for (int r = 0; r < 4; ++r)
            if (lg * 4 + r > lr) sc[ct][r] = -1e30f;
    }

    // ---- online softmax, exp2 domain, per-lane scalar state (q = lr)
    float mx = -3e38f;
#pragma unroll
    for (int ct = 0; ct < 4; ++ct)
      if (ct < nct)
#pragma unroll
        for (int r = 0; r < 4; ++r) mx = fmaxf(mx, sc[ct][r]);
    mx = fmaxf(mx, __shfl_xor(mx, 16, 64));
    mx = fmaxf(mx, __shfl_xor(mx, 32, 64));
    const float mnew = fmaxf(m_, mx);
    const float fs = __builtin_exp2f(m_ - mnew);
    m_ = mnew;
#pragma unroll
    for (int ct = 0; ct < 4; ++ct) {
      if (ct < nct) {
        float p0 = __builtin_exp2f(sc[ct][0] - m_);
        float p1 = __builtin_exp2f(sc[ct][1] - m_);
        float p2 = __builtin_exp2f(sc[ct][2] - m_);
        float p3 = __builtin_exp2f(sc[ct][3] - m_);
        us4 pk;
        pk[0] = f2bf(p0); pk[1] = f2bf(p1); pk[2] = f2bf(p2); pk[3] = f2bf(p3);
        // P[q = lr][k = ct*16 + lg*4 .. +4]  (one 8B write)
        *(us4*)&P[lr * 72 + ct * 16 + lg * 4] = pk;
      } else {
        us4 zz = {};  // masked k-subtile on diag: exact zeros
        *(us4*)&P[lr * 72 + ct * 16 + lg * 4] = zz;
      }
    }

    // ---- rescale O^T and l (all state at q = lr: direct, no shuffles)
#pragma unroll
    for (int dj = 0; dj < 4; ++dj)
#pragma unroll
      for (int r = 0; r < 4; ++r) o[dj][r] *= fs;
    l4[0] *= fs;

    // LDS write->read ordering within the wave
    asm volatile("s_waitcnt lgkmcnt(0)" ::: "memory");
    bf16x8 pa[2];
#pragma unroll
    for (int ksp = 0; ksp < 2; ++ksp)
      pa[ksp] = *(const bf16x8*)&P[lr * 72 + ksp * 32 + lg * 8];

    // ---- l += rowsum(P) via ones-MFMA: D[m][n=lr] = sum_k P[lr][k]
#pragma unroll
    for (int ksp = 0; ksp < 2; ++ksp)
      l4 = __builtin_amdgcn_mfma_f32_16x16x32_bf16(onesv, pa[ksp], l4, 0, 0, 0);
    // ---- O^T += V^T P^T : D[d_local][q=lr]
#pragma unroll
    for (int dj = 0; dj < 4; ++dj)
#pragma unroll
      for (int ksp = 0; ksp < 2; ++ksp)
        o[dj] = __builtin_amdgcn_mfma_f32_16x16x32_bf16(vt[dj][ksp], pa[ksp],
                                                        o[dj], 0, 0, 0);

    __syncthreads();  // stage(t+1) complete (vmcnt0) + buffer handoff
  }

  // ---- normalize and write AO [b*S+s][h*64+d] bf16 (8B packed over d)
  const int bb = bh >> 4, hh = bh & 15;
  const float inv = 1.0f / l4[0];
#pragma unroll
  for (int dj = 0; dj < 4; ++dj) {
    us4 pk;
#pragma unroll
    for (int r = 0; r < 4; ++r) pk[r] = f2bf(o[dj][r] * inv);
    *(us4*)&AO[((size_t)bb * Ss + q0 + lr) * Dd + hh * 64 + dj * 16 + lg * 4] =
        pk;
  }
}

// ---------------------------------------------------------------- launch
extern "C" void kernel_launch(void* const* d_in, const int* in_sizes, int n_in,
                              void* d_out, int out_size, void* d_ws, size_t ws_size,
                              hipStream_t stream) {
  const float* x  = (const float*)d_in[0];
  // d_in[1] = causal mask (tril) — hardcoded in attn kernel
  const float* wq = (const float*)d_in[2];
  const float* bq = (const float*)d_in[3];
  const float* wk = (const float*)d_in[4];
  const float* bk = (const float*)d_in[5];
  const float* wv = (const float*)d_in[6];
  const float* bv = (const float*)d_in[7];
  const float* wo = (const float*)d_in[8];
  const float* bo = (const float*)d_in[9];

  ushort_t* ws   = (ushort_t*)d_ws;
  ushort_t* xb   = ws;                   // [4096][1024] bf16 (8MB), reused as AO
  ushort_t* wqkv = xb + 4096 * 1024;     // [3072][1024] bf16 (6MB)
  ushort_t* wob  = wqkv + 3072 * 1024;   // [1024][1024] bf16 (2MB), contiguous
  ushort_t* Qb   = wob + 1024 * 1024;    // [2,16,2048,64] bf16 (8MB)
  ushort_t* Kb   = Qb + 4194304;         // (8MB)
  ushort_t* VTb  = Kb + 4194304;         // [2,16,64,2048] bf16 (8MB)
  ushort_t* AOb  = xb;                   // reuse: x dead after QKV GEMM

  cast_all<<<4096, 256, 0, stream>>>(x, wq, wk, wv, wo, xb, wqkv);

  gemm0_k<<<dim3(24, 32), 256, 0, stream>>>(xb, wqkv, bq, bk, bv, Qb, Kb, VTb);
  attn_k<<<1024, 256, 0, stream>>>(Qb, Kb, VTb, AOb);
  gemm1_k<<<dim3(16, 32), 256, 0, stream>>>(AOb, wob, bo, (float*)d_out);
}